// Round 8
// baseline (137.637 us; speedup 1.0000x reference)
//
#include <hip/hip_runtime.h>
#include <hip/hip_bf16.h>
#include <stdint.h>

#define XLEN   262144
#define NT     513
#define NTP    528               // padded frames per batch (8*528 = 4224 = 33*128)
#define NB     8
#define NCOL   (NB * NTP)        // 4224 fused columns
#define NK     1088              // direct freq rows k = 0..1087 (17 tiles of 64)
#define NFFT   2048
#define OUTKT  (2048 * NT)
#define NWG    561               // 17 * 33
#define BUFS   8192              // shorts per LDS B-buffer (16 KiB): 128 rows x 64 shorts

typedef __attribute__((ext_vector_type(8))) short short8;
typedef __attribute__((ext_vector_type(4))) float f32x4;

__device__ __forceinline__ short cvt_bf16(float f) {
  return __builtin_bit_cast(short, (__bf16)f);
}

__device__ __forceinline__ void gload16(const short* g, const short* l) {
  __builtin_amdgcn_global_load_lds(
      (const __attribute__((address_space(1))) void*)g,
      (__attribute__((address_space(3))) void*)l, 16, 0, 0);
}

// ---------------- prep: fp32 weights (rows 0..1087) -> bf16 ----------------
__global__ __launch_bounds__(256) void conv_w_kernel(const float* __restrict__ wsin,
                                                     const float* __restrict__ wcos,
                                                     short* __restrict__ wc,
                                                     short* __restrict__ ws) {
  const int row = blockIdx.x;
  const int c = threadIdx.x * 8;
  const float* src = (blockIdx.y ? wsin : wcos) + (size_t)row * NFFT + c;
  short* dst = (blockIdx.y ? ws : wc) + (size_t)row * NFFT + c;
  f32x4 a = *(const f32x4*)src;
  f32x4 b = *(const f32x4*)(src + 4);
  short8 o;
#pragma unroll
  for (int j = 0; j < 4; ++j) { o[j] = cvt_bf16(a[j]); o[4 + j] = cvt_bf16(b[j]); }
  *(short8*)dst = o;
}

// ---------------- prep: reflect-padded frames -> bf16 [4224][2048] ----------------
__global__ __launch_bounds__(256) void conv_frames_kernel(const float* __restrict__ x,
                                                          short* __restrict__ fr) {
  const int j = blockIdx.x;
  const int b = j / NTP;
  const int t = j - b * NTP;
  const int c = threadIdx.x * 8;
  short8 o;
  if (t >= NT) {
#pragma unroll
    for (int k = 0; k < 8; ++k) o[k] = 0;
  } else {
    const float* xb = x + (size_t)b * XLEN;
    const int base = t * 512 + c - 1024;
    float v[8];
    if (base >= 0 && base + 7 < XLEN) {
      *(f32x4*)(v)     = *(const f32x4*)(xb + base);
      *(f32x4*)(v + 4) = *(const f32x4*)(xb + base + 4);
    } else {
#pragma unroll
      for (int k = 0; k < 8; ++k) {
        int m = base + k;
        m = (m < 0) ? -m : m;
        m = (m >= XLEN) ? (2 * XLEN - 2 - m) : m;
        v[k] = xb[m];
      }
    }
#pragma unroll
    for (int k = 0; k < 8; ++k) o[k] = cvt_bf16(v[k]);
  }
  *(short8*)&fr[(size_t)j * NFFT + c] = o;
}

// ---------------- main GEMM ----------------
// BM=64 (k), BN=128 (j), BK=64. 4 waves 2x2; each wave 32x64 per matrix.
// A (wcos+wsin) fragments loaded DIRECT from global (L2-hot via k0-major
// XCD swizzle), register-double-buffered -> LDS holds only B (frames):
// per block-step LDS traffic 96KB -> 48KB (the R4-R7 critical path).
// B: 2 x 16 KiB LDS dbuf, gload_lds with (row&7) 16B-chunk XOR swizzle on
// global source + ds_read side (rule #21; verified R4/R6).
// Counted vmcnt: per iter issue 4 B-gloads then 8 A-loads; vmcnt(8) drains
// last iter's loads + this iter's B, leaves this iter's A in flight.
template <bool WS>
__global__ __launch_bounds__(256, 2) void dft_gemm_kernel(
    const float* __restrict__ x,
    const float* __restrict__ wsin_f,
    const float* __restrict__ wcos_f,
    const short* __restrict__ wc_bf,
    const short* __restrict__ ws_bf,
    const short* __restrict__ fr_bf,
    float* __restrict__ outR,
    float* __restrict__ outI) {
  __shared__ short lds[2 * BUFS];  // 32 KiB (B only)

  const int tid  = threadIdx.x;
  const int lane = tid & 63;
  const int wid  = tid >> 6;

  // T1: bijective XCD swizzle (m204), k0-major within XCD so co-resident
  // blocks on one XCD share 2-3 weight k-tiles (A stays L2-hot).
  const int o   = blockIdx.x;
  const int xcd = o & 7;
  const int wg  = ((xcd < 1) ? xcd * 71 : 71 + (xcd - 1) * 70) + (o >> 3);
  const int k0  = (wg / 33) * 64;
  const int j0  = (wg % 33) * 128;

  const int wrow = (wid >> 1) * 32;  // k-offset of this wave
  const int wcol = (wid & 1) * 64;   // j-offset of this wave

  f32x4 accR[2][4], accI[2][4];
#pragma unroll
  for (int m = 0; m < 2; ++m)
#pragma unroll
    for (int n = 0; n < 4; ++n) { accR[m][n] = (f32x4)0.0f; accI[m][n] = (f32x4)0.0f; }

  const int fr_r = lane & 15;        // fragment row
  const int fk   = (lane >> 4) * 8;  // k-offset (shorts) within 32
  const int srow = lane >> 3;        // 0..7 within an 8-row staging chunk
  const int scol = ((lane & 7) ^ srow) * 8;  // swizzled source 16B-chunk

  // ---- B staging: 16 chunks of (8 rows x 64 shorts); 4 gloads per wave ----
  auto stageB = [&](int n0, int bb) {
#pragma unroll
    for (int i = 0; i < 4; ++i) {
      const int q = wid * 4 + i;  // 0..15, wave-uniform
      if (WS) {
        const short* src = fr_bf + (size_t)(j0 + q * 8 + srow) * NFFT + n0 + scol;
        gload16(src, &lds[bb + q * 512]);
      } else {
        const int row = q * 8 + srow;
        const int jj = j0 + row;
        const int b = jj / NTP, t = jj - b * NTP;
        short8 v;
        if (t < NT) {
          const float* xb = x + (size_t)b * XLEN;
          const int base = t * 512 + n0 + scol - 1024;
          float fv[8];
          if (base >= 0 && base + 7 < XLEN) {
            *(f32x4*)(fv)     = *(const f32x4*)(xb + base);
            *(f32x4*)(fv + 4) = *(const f32x4*)(xb + base + 4);
          } else {
#pragma unroll
            for (int k = 0; k < 8; ++k) {
              int m = base + k;
              m = (m < 0) ? -m : m;
              m = (m >= XLEN) ? (2 * XLEN - 2 - m) : m;
              fv[k] = xb[m];
            }
          }
#pragma unroll
          for (int k = 0; k < 8; ++k) v[k] = cvt_bf16(fv[k]);
        } else {
#pragma unroll
          for (int k = 0; k < 8; ++k) v[k] = 0;
        }
        *(short8*)&lds[bb + q * 512 + lane * 8] = v;
      }
    }
  };

  // ---- A fragments direct from global: 8 loads (4 cos + 4 sin) ----
  auto loadA = [&](int n0, short8 (*ac)[2], short8 (*as_)[2]) {
#pragma unroll
    for (int ks = 0; ks < 2; ++ks)
#pragma unroll
      for (int m = 0; m < 2; ++m) {
        const size_t off = (size_t)(k0 + wrow + m * 16 + fr_r) * NFFT + n0 + ks * 32 + fk;
        if (WS) {
          ac[ks][m]  = *(const short8*)&wc_bf[off];
          as_[ks][m] = *(const short8*)&ws_bf[off];
        } else {
          const float* pc = wcos_f + off;
          const float* ps = wsin_f + off;
          f32x4 c0 = *(const f32x4*)pc, c1 = *(const f32x4*)(pc + 4);
          f32x4 s0 = *(const f32x4*)ps, s1 = *(const f32x4*)(ps + 4);
          short8 vc, vs;
#pragma unroll
          for (int jx = 0; jx < 4; ++jx) {
            vc[jx] = cvt_bf16(c0[jx]); vc[4 + jx] = cvt_bf16(c1[jx]);
            vs[jx] = cvt_bf16(s0[jx]); vs[4 + jx] = cvt_bf16(s1[jx]);
          }
          ac[ks][m] = vc;
          as_[ks][m] = vs;
        }
      }
  };

  short8 aC[2][2][2], aS[2][2][2];  // [parity][ks][m] - static indexing only

  loadA(0, aC[0], aS[0]);
  stageB(0, 0);

#pragma unroll 2
  for (int t = 0; t < 32; ++t) {
    const int bb = (t & 1) * BUFS;
    const int p  = t & 1;        // compile-time constant under unroll 2
    const int pn = p ^ 1;
    if (t < 31) {
      stageB((t + 1) * 64, bb ^ BUFS);           // 4 gload_lds (oldest this iter)
      __builtin_amdgcn_sched_barrier(0);
      loadA((t + 1) * 64, aC[pn], aS[pn]);       // 8 reg loads (newest this iter)
    }
    if (WS) {
      __builtin_amdgcn_sched_barrier(0);
      // drain last iter's A+B and this iter's B; keep this iter's 8 A-loads
      // in flight across the barrier (they're needed only next iteration).
      if (t < 31) asm volatile("s_waitcnt vmcnt(8)" ::: "memory");
      else        asm volatile("s_waitcnt vmcnt(0)" ::: "memory");
      __builtin_amdgcn_s_barrier();
      __builtin_amdgcn_sched_barrier(0);
    } else {
      __syncthreads();
    }
    // ---- compute: per substep 4 ds_read_b128 (B only) + 16 MFMA ----
#pragma unroll
    for (int ks = 0; ks < 2; ++ks) {
      const int cc = ks * 4 + (lane >> 4);  // 16B-chunk within 64-short row
      short8 b_f[4];
#pragma unroll
      for (int n = 0; n < 4; ++n) {
        const int r = wcol + n * 16 + fr_r;
        const int off = bb + (r << 6) + ((cc ^ (r & 7)) << 3);
        b_f[n] = *(const short8*)&lds[off];
      }
#pragma unroll
      for (int m = 0; m < 2; ++m)
#pragma unroll
        for (int n = 0; n < 4; ++n) {
          accR[m][n] = __builtin_amdgcn_mfma_f32_16x16x32_bf16(aC[p][ks][m], b_f[n], accR[m][n], 0, 0, 0);
          accI[m][n] = __builtin_amdgcn_mfma_f32_16x16x32_bf16(aS[p][ks][m], b_f[n], accI[m][n], 0, 0, 0);
        }
    }
    if (WS) {
      // all reads of lds[bb] consumed -> barrier frees bb. No vmcnt drain.
      __builtin_amdgcn_sched_barrier(0);
      __builtin_amdgcn_s_barrier();
    } else {
      __syncthreads();
    }
  }

  // ---- epilogue: direct rows + Hermitian mirror (k in [1,960] -> 2048-k) ----
#pragma unroll
  for (int m = 0; m < 2; ++m) {
    const int k = k0 + wrow + m * 16 + (lane >> 4) * 4;
#pragma unroll
    for (int n = 0; n < 4; ++n) {
      const int j = j0 + wcol + n * 16 + (lane & 15);
      const int b = j / NTP;
      const int t = j - b * NTP;
      if (t < NT) {
        const size_t base = (size_t)b * OUTKT + (size_t)k * NT + t;
#pragma unroll
        for (int r = 0; r < 4; ++r) {
          const int kk = k + r;
          const float vr = accR[m][n][r];
          const float vi = accI[m][n][r];
          outR[base + (size_t)r * NT] = vr;
          outI[base + (size_t)r * NT] = -vi;
          if (kk >= 1 && kk <= 960) {
            const size_t mb = (size_t)b * OUTKT + (size_t)(2048 - kk) * NT + t;
            outR[mb] = vr;   // cos mirror: equal
            outI[mb] = vi;   // -(-imag): sin mirror negated
          }
        }
      }
    }
  }
}

extern "C" void kernel_launch(void* const* d_in, const int* in_sizes, int n_in,
                              void* d_out, int out_size, void* d_ws, size_t ws_size,
                              hipStream_t stream) {
  const float* x    = (const float*)d_in[0];
  const float* wsin = (const float*)d_in[1];
  const float* wcos = (const float*)d_in[2];
  float* outR = (float*)d_out;
  float* outI = outR + (size_t)NB * OUTKT;

  short* wc_bf = (short*)d_ws;
  short* ws_bf = wc_bf + (size_t)NK * NFFT;
  short* fr_bf = ws_bf + (size_t)NK * NFFT;
  const size_t ws_need = ((size_t)2 * NK + NCOL) * NFFT * sizeof(short);  // ~26.2 MB

  if (ws_size >= ws_need) {
    conv_w_kernel<<<dim3(NK, 2), 256, 0, stream>>>(wsin, wcos, wc_bf, ws_bf);
    conv_frames_kernel<<<NCOL, 256, 0, stream>>>(x, fr_bf);
    dft_gemm_kernel<true><<<NWG, 256, 0, stream>>>(x, wsin, wcos, wc_bf, ws_bf, fr_bf, outR, outI);
  } else {
    dft_gemm_kernel<false><<<NWG, 256, 0, stream>>>(x, wsin, wcos, wc_bf, ws_bf, fr_bf, outR, outI);
  }
}

// Round 9
// 88.314 us; speedup vs baseline: 1.5585x; 1.5585x over previous
//
#include <hip/hip_runtime.h>
#include <hip/hip_bf16.h>
#include <stdint.h>

#define XLEN   262144
#define NT     513
#define NTP    528               // padded frames per batch (8*528 = 4224 = 33*128)
#define NB     8
#define NCOL   (NB * NTP)        // 4224 fused columns
#define NKC    576               // padded computed k rows (valid: 0..512)
#define KH     1024              // half transform length (radix-2)
#define NFFT   2048
#define OUTKT  (2048 * NT)
#define NWG    297               // 9 * 33

typedef __attribute__((ext_vector_type(8))) short short8;
typedef __attribute__((ext_vector_type(4))) short short4v;
typedef __attribute__((ext_vector_type(4))) float f32x4;

__device__ __forceinline__ short cvt_bf16(float f) {
  return __builtin_bit_cast(short, (__bf16)f);
}

__device__ __forceinline__ void gload16(const short* g, const short* l) {
  __builtin_amdgcn_global_load_lds(
      (const __attribute__((address_space(1))) void*)g,
      (__attribute__((address_space(3))) void*)l, 16, 0, 0);
}

// ---- prep: split weights rows 0..512 by sample parity -> 4 bf16 mats [576][1024] ----
__global__ __launch_bounds__(256) void conv_w_split(
    const float* __restrict__ wsin, const float* __restrict__ wcos,
    short* __restrict__ wcE, short* __restrict__ wsE,
    short* __restrict__ wcO, short* __restrict__ wsO) {
  const int row = blockIdx.x;
  const int m0 = threadIdx.x * 4;
  short4v ce, se, co, so;
  if (row <= 512) {
    const float* pc = wcos + (size_t)row * NFFT + m0 * 2;
    const float* ps = wsin + (size_t)row * NFFT + m0 * 2;
    f32x4 c0 = *(const f32x4*)pc, c1 = *(const f32x4*)(pc + 4);
    f32x4 s0 = *(const f32x4*)ps, s1 = *(const f32x4*)(ps + 4);
    ce[0] = cvt_bf16(c0[0]); ce[1] = cvt_bf16(c0[2]); ce[2] = cvt_bf16(c1[0]); ce[3] = cvt_bf16(c1[2]);
    co[0] = cvt_bf16(c0[1]); co[1] = cvt_bf16(c0[3]); co[2] = cvt_bf16(c1[1]); co[3] = cvt_bf16(c1[3]);
    se[0] = cvt_bf16(s0[0]); se[1] = cvt_bf16(s0[2]); se[2] = cvt_bf16(s1[0]); se[3] = cvt_bf16(s1[2]);
    so[0] = cvt_bf16(s0[1]); so[1] = cvt_bf16(s0[3]); so[2] = cvt_bf16(s1[1]); so[3] = cvt_bf16(s1[3]);
  } else {
#pragma unroll
    for (int e = 0; e < 4; ++e) { ce[e] = 0; se[e] = 0; co[e] = 0; so[e] = 0; }
  }
  const size_t o = (size_t)row * KH + m0;
  *(short4v*)&wcE[o] = ce; *(short4v*)&wsE[o] = se;
  *(short4v*)&wcO[o] = co; *(short4v*)&wsO[o] = so;
}

// ---- prep: reflect-padded frames split by parity -> bf16 [4224][1024] x2 ----
__global__ __launch_bounds__(256) void conv_fr_split(const float* __restrict__ x,
                                                     short* __restrict__ frE,
                                                     short* __restrict__ frO) {
  const int j = blockIdx.x;
  const int b = j / NTP;
  const int t = j - b * NTP;
  const int m0 = threadIdx.x * 4;
  short4v ve, vo;
  if (t < NT) {
    const float* xb = x + (size_t)b * XLEN;
    const int q0 = t * 512 + 2 * m0 - 1024;
    float v[8];
    if (q0 >= 0 && q0 + 7 < XLEN) {
      *(f32x4*)(v)     = *(const f32x4*)(xb + q0);
      *(f32x4*)(v + 4) = *(const f32x4*)(xb + q0 + 4);
    } else {
#pragma unroll
      for (int e = 0; e < 8; ++e) {
        int mm = q0 + e;
        mm = (mm < 0) ? -mm : mm;
        mm = (mm >= XLEN) ? (2 * XLEN - 2 - mm) : mm;
        v[e] = xb[mm];
      }
    }
#pragma unroll
    for (int e = 0; e < 4; ++e) { ve[e] = cvt_bf16(v[2 * e]); vo[e] = cvt_bf16(v[2 * e + 1]); }
  } else {
#pragma unroll
    for (int e = 0; e < 4; ++e) { ve[e] = 0; vo[e] = 0; }
  }
  *(short4v*)&frE[(size_t)j * KH + m0] = ve;
  *(short4v*)&frO[(size_t)j * KH + m0] = vo;
}

// ---------------- main GEMM (radix-2 + Hermitian) ----------------
// Computes EC,ES,OC,OS[k,j] for k in [0,576) (valid 0..512), j in [0,4224),
// K=1024. BM=64, BN=128, BK=64; 4 waves 2x2, per wave 32x64 per matrix.
// Per substep: 16 ds_read_b128 (8 A + 8 B) : 32 MFMA. LDS single buffer 64KB:
// [wcE 64x64 | wsE | wcO | wsO | frE 128x64 | frO 128x64], rows 64 shorts,
// 16B-chunk XOR-swizzle (row&7) on global source + ds_read side (rule #21).
// Epilogue: X_k = E + O', X_{k+1024} = E - O', plus Hermitian mirrors.
template <bool WS>
__global__ __launch_bounds__(256, 2) void dft_gemm_kernel(
    const float* __restrict__ x,
    const float* __restrict__ wsin_f,
    const float* __restrict__ wcos_f,
    const short* __restrict__ wcE_g, const short* __restrict__ wsE_g,
    const short* __restrict__ wcO_g, const short* __restrict__ wsO_g,
    const short* __restrict__ frE_g, const short* __restrict__ frO_g,
    float* __restrict__ outR,
    float* __restrict__ outI) {
  __shared__ short lds[32768];  // 64 KiB

  const int tid  = threadIdx.x;
  const int lane = tid & 63;
  const int wid  = tid >> 6;

  // T1: bijective XCD swizzle (m204). nwg=297, q=37, r=1. k-sweep within XCD.
  const int o   = blockIdx.x;
  const int xcd = o & 7;
  const int wg  = ((xcd < 1) ? xcd * 38 : 38 + (xcd - 1) * 37) + (o >> 3);
  const int k0  = (wg % 9) * 64;
  const int j0  = (wg / 9) * 128;

  const int wrow = (wid >> 1) * 32;  // k-offset of this wave
  const int wcol = (wid & 1) * 64;   // j-offset of this wave

  f32x4 accEC[2][4], accES[2][4], accOC[2][4], accOS[2][4];
#pragma unroll
  for (int m = 0; m < 2; ++m)
#pragma unroll
    for (int n = 0; n < 4; ++n) {
      accEC[m][n] = (f32x4)0.0f; accES[m][n] = (f32x4)0.0f;
      accOC[m][n] = (f32x4)0.0f; accOS[m][n] = (f32x4)0.0f;
    }

  const int fr_r = lane & 15;        // fragment row
  const int srow = lane >> 3;        // 0..7 within an 8-row staging chunk
  const int scol = ((lane & 7) ^ srow) * 8;  // swizzled source 16B-chunk

  // one buffer = 64 chunks of (8 rows x 64 shorts = 1 KiB); 16 per wave.
  // q: 0..7 wcE | 8..15 wsE | 16..23 wcO | 24..31 wsO | 32..47 frE | 48..63 frO
  auto stage = [&](int n0) {
#pragma unroll
    for (int i = 0; i < 16; ++i) {
      const int q = wid * 16 + i;  // wave-uniform
      if (WS) {
        const short* src;
        int dst;
        if (q < 8)       { src = wcE_g + (size_t)(k0 + (q & 7) * 8 + srow) * KH + n0 + scol; dst = (q & 7) * 512; }
        else if (q < 16) { src = wsE_g + (size_t)(k0 + (q & 7) * 8 + srow) * KH + n0 + scol; dst = 4096  + (q & 7) * 512; }
        else if (q < 24) { src = wcO_g + (size_t)(k0 + (q & 7) * 8 + srow) * KH + n0 + scol; dst = 8192  + (q & 7) * 512; }
        else if (q < 32) { src = wsO_g + (size_t)(k0 + (q & 7) * 8 + srow) * KH + n0 + scol; dst = 12288 + (q & 7) * 512; }
        else if (q < 48) { src = frE_g + (size_t)(j0 + (q & 15) * 8 + srow) * KH + n0 + scol; dst = 16384 + (q & 15) * 512; }
        else             { src = frO_g + (size_t)(j0 + (q & 15) * 8 + srow) * KH + n0 + scol; dst = 24576 + (q & 15) * 512; }
        gload16(src, &lds[dst]);
      } else {
        short8 v;
        int dst;
        if (q < 32) {
          const int mat = q >> 3;          // 0 cE, 1 sE, 2 cO, 3 sO
          const int par = mat >> 1;
          const int row = k0 + (q & 7) * 8 + srow;
          const float* wsrc = (mat & 1) ? wsin_f : wcos_f;
          if (row <= 512) {
#pragma unroll
            for (int e = 0; e < 8; ++e)
              v[e] = cvt_bf16(wsrc[(size_t)row * NFFT + 2 * (n0 + scol + e) + par]);
          } else {
#pragma unroll
            for (int e = 0; e < 8; ++e) v[e] = 0;
          }
          dst = mat * 4096 + (q & 7) * 512 + lane * 8;
        } else {
          const int par = (q >= 48);
          const int ch = q & 15;
          const int jj = j0 + ch * 8 + srow;
          const int b = jj / NTP, t = jj - b * NTP;
          if (t < NT) {
            const float* xb = x + (size_t)b * XLEN;
#pragma unroll
            for (int e = 0; e < 8; ++e) {
              int mm = t * 512 + 2 * (n0 + scol + e) + par - 1024;
              mm = (mm < 0) ? -mm : mm;
              mm = (mm >= XLEN) ? (2 * XLEN - 2 - mm) : mm;
              v[e] = cvt_bf16(xb[mm]);
            }
          } else {
#pragma unroll
            for (int e = 0; e < 8; ++e) v[e] = 0;
          }
          dst = (par ? 24576 : 16384) + ch * 512 + lane * 8;
        }
        *(short8*)&lds[dst] = v;
      }
    }
  };

  for (int ts = 0; ts < 16; ++ts) {
    if (ts) __syncthreads();
    stage(ts * 64);
    __syncthreads();
#pragma unroll
    for (int ks = 0; ks < 2; ++ks) {
      const int cc = ks * 4 + (lane >> 4);  // 16B-chunk within 64-short row
      short8 aCE[2], aSE[2], aCO[2], aSO[2], bE[4], bO[4];
#pragma unroll
      for (int m = 0; m < 2; ++m) {
        const int r = wrow + m * 16 + fr_r;
        const int off = (r << 6) + ((cc ^ (r & 7)) << 3);
        aCE[m] = *(const short8*)&lds[off];
        aSE[m] = *(const short8*)&lds[4096 + off];
        aCO[m] = *(const short8*)&lds[8192 + off];
        aSO[m] = *(const short8*)&lds[12288 + off];
      }
#pragma unroll
      for (int n = 0; n < 4; ++n) {
        const int r = wcol + n * 16 + fr_r;
        const int off = (r << 6) + ((cc ^ (r & 7)) << 3);
        bE[n] = *(const short8*)&lds[16384 + off];
        bO[n] = *(const short8*)&lds[24576 + off];
      }
#pragma unroll
      for (int m = 0; m < 2; ++m)
#pragma unroll
        for (int n = 0; n < 4; ++n) {
          accEC[m][n] = __builtin_amdgcn_mfma_f32_16x16x32_bf16(aCE[m], bE[n], accEC[m][n], 0, 0, 0);
          accES[m][n] = __builtin_amdgcn_mfma_f32_16x16x32_bf16(aSE[m], bE[n], accES[m][n], 0, 0, 0);
          accOC[m][n] = __builtin_amdgcn_mfma_f32_16x16x32_bf16(aCO[m], bO[n], accOC[m][n], 0, 0, 0);
          accOS[m][n] = __builtin_amdgcn_mfma_f32_16x16x32_bf16(aSO[m], bO[n], accOS[m][n], 0, 0, 0);
        }
    }
  }

  // ---- epilogue: combine E/O' and write 4 output row groups ----
  // X_k = E + O' ; X_{k+1024} = E - O' ; Hermitian: C_{2048-k}=C_k, S_{2048-k}=-S_k.
  // outR = C, outI = -S.
#pragma unroll
  for (int m = 0; m < 2; ++m) {
    const int kb = k0 + wrow + m * 16 + (lane >> 4) * 4;
#pragma unroll
    for (int n = 0; n < 4; ++n) {
      const int j = j0 + wcol + n * 16 + (lane & 15);
      const int b = j / NTP;
      const int t = j - b * NTP;
      if (t < NT) {
        const size_t bb = (size_t)b * OUTKT + t;
#pragma unroll
        for (int r = 0; r < 4; ++r) {
          const int k = kb + r;
          if (k > 512) continue;
          const float EC = accEC[m][n][r], ES = accES[m][n][r];
          const float OC = accOC[m][n][r], OS = accOS[m][n][r];
          const float c1 = EC + OC, s1 = ES + OS;   // C_k, S_k
          const float c2 = EC - OC, s2 = ES - OS;   // C_{1024+k}, S_{1024+k}
          outR[bb + (size_t)k * NT] = c1;
          outI[bb + (size_t)k * NT] = -s1;
          if (k >= 1) {
            outR[bb + (size_t)(2048 - k) * NT] = c1;
            outI[bb + (size_t)(2048 - k) * NT] = s1;
          }
          outR[bb + (size_t)(1024 + k) * NT] = c2;
          outI[bb + (size_t)(1024 + k) * NT] = -s2;
          if (k >= 1) {
            outR[bb + (size_t)(1024 - k) * NT] = c2;
            outI[bb + (size_t)(1024 - k) * NT] = s2;
          }
        }
      }
    }
  }
}

extern "C" void kernel_launch(void* const* d_in, const int* in_sizes, int n_in,
                              void* d_out, int out_size, void* d_ws, size_t ws_size,
                              hipStream_t stream) {
  const float* x    = (const float*)d_in[0];
  const float* wsin = (const float*)d_in[1];
  const float* wcos = (const float*)d_in[2];
  float* outR = (float*)d_out;
  float* outI = outR + (size_t)NB * OUTKT;

  short* wcE = (short*)d_ws;
  short* wsE = wcE + (size_t)NKC * KH;
  short* wcO = wsE + (size_t)NKC * KH;
  short* wsO = wcO + (size_t)NKC * KH;
  short* frE = wsO + (size_t)NKC * KH;
  short* frO = frE + (size_t)NCOL * KH;
  const size_t ws_need = ((size_t)4 * NKC + 2 * NCOL) * KH * sizeof(short);  // ~22 MB

  if (ws_size >= ws_need) {
    conv_w_split<<<NKC, 256, 0, stream>>>(wsin, wcos, wcE, wsE, wcO, wsO);
    conv_fr_split<<<NCOL, 256, 0, stream>>>(x, frE, frO);
    dft_gemm_kernel<true><<<NWG, 256, 0, stream>>>(x, wsin, wcos, wcE, wsE, wcO, wsO, frE, frO, outR, outI);
  } else {
    dft_gemm_kernel<false><<<NWG, 256, 0, stream>>>(x, wsin, wcos, wcE, wsE, wcO, wsO, frE, frO, outR, outI);
  }
}